// Round 3
// baseline (395.591 us; speedup 1.0000x reference)
//
#include <hip/hip_runtime.h>

// Problem constants
#define NB     64      // batch
#define TT     2048    // time
#define INQ    8       // input size
#define CC     2       // channels
#define MM     10      // hidden m
#define TS     2047    // time steps = T-1
#define ROWP   12      // padded row floats (48 B, 16-aligned)
#define MATP   (MM*ROWP)   // 120 floats per padded matrix
#define SLEN   4       // sequential steps per lane-pair segment
#define SEGS   128     // segments per block
#define CHUNK  (SEGS*SLEN) // 512 steps per block
#define NCHUNK 4       // chunks per chain
#define NCHAIN (NB*CC)
#define KTAY   7       // Taylor order

__device__ __forceinline__ float dpp_xor1(float v) {
    // swap with partner lane (lane ^ 1) via DPP quad_perm [1,0,3,2] = 0xB1
    int i = __float_as_int(v);
    int r = __builtin_amdgcn_update_dpp(i, i, 0xB1, 0xF, 0xF, true);
    return __int_as_float(r);
}

// Upper-triangle index for (k,j), k<j, into 45-element array
__device__ __forceinline__ constexpr int triIdx(int k, int j) {
    return k * 10 + j - ((k + 1) * (k + 2)) / 2;
}

// One block per (chain, chunk). Lane pair processes SLEN steps serially:
// R <- R * expm(G_t) via row-independent S-Horner with G stored as its
// 45-value upper triangle in registers (skew-symmetry; lower = -upper via
// FMA negate modifiers). Then 7-level dyadic LDS tree -> chunk product.
__global__ __launch_bounds__(256) __attribute__((amdgpu_waves_per_eu(2, 2)))
void dev_serial(const float* __restrict__ x,
                const float* __restrict__ A,
                float* __restrict__ ws)
{
    __shared__ float skew_s[INQ * MATP];   // 3840 B
    __shared__ float tree_s[SEGS * MATP];  // 61440 B (total 65280 <= 64 KiB)

    const int tid   = threadIdx.x;
    const int chain = blockIdx.x >> 2;   // / NCHUNK
    const int chunk = blockIdx.x & 3;
    const int n     = chain >> 1;        // / CC
    const int c     = chain & 1;

    // Stage skew = A - A^T for our channel, padded rows (pad = 0)
    for (int e = tid; e < INQ * MATP; e += 256) {
        const int ip  = e / MATP;
        const int rem = e - ip * MATP;
        const int i   = rem / ROWP;
        const int j   = rem - i * ROWP;
        float v = 0.0f;
        if (j < MM) {
            const float* Ab = A + (size_t)(c * INQ + ip) * (MM * MM);
            v = Ab[i * MM + j] - Ab[j * MM + i];
        }
        skew_s[e] = v;
    }
    __syncthreads();

    const int seg = tid >> 1;
    const int p   = tid & 1;     // parity: this lane owns global rows r0..r0+4
    const int r0  = p * 5;

    // Running product rows (identity init)
    float R[5][MM];
    #pragma unroll
    for (int r = 0; r < 5; ++r)
        #pragma unroll
        for (int j = 0; j < MM; ++j)
            R[r][j] = (j == r0 + r) ? 1.0f : 0.0f;

    const float* xb = x + (size_t)n * TT * INQ;
    int t = chunk * CHUNK + seg * SLEN;

    float xc[INQ];
    {
        const float4* xp = reinterpret_cast<const float4*>(xb + (size_t)t * INQ);
        float4 a = xp[0], b = xp[1];
        xc[0] = a.x; xc[1] = a.y; xc[2] = a.z; xc[3] = a.w;
        xc[4] = b.x; xc[5] = b.y; xc[6] = b.z; xc[7] = b.w;
    }

    #pragma unroll 1
    for (int s = 0; s < SLEN; ++s) {
        // next x (clamped: t+1 == 2048 -> reuse last -> dx = 0 -> E = I)
        int tn = t + 1; if (tn > TS) tn = TS;
        float dx[INQ];
        {
            const float4* xp = reinterpret_cast<const float4*>(xb + (size_t)tn * INQ);
            float4 a = xp[0], b = xp[1];
            dx[0] = a.x - xc[0]; dx[1] = a.y - xc[1]; dx[2] = a.z - xc[2]; dx[3] = a.w - xc[3];
            dx[4] = b.x - xc[4]; dx[5] = b.y - xc[5]; dx[6] = b.z - xc[6]; dx[7] = b.w - xc[7];
            xc[0] = a.x; xc[1] = a.y; xc[2] = a.z; xc[3] = a.w;
            xc[4] = b.x; xc[5] = b.y; xc[6] = b.z; xc[7] = b.w;
        }
        t = t + 1;

        // Build gm[s][j] for j > s only. Register gm[s][j] holds, on lane p,
        // G[r0+s][j] (row r0+s of G). Lane 0 needs j>s of its rows; lane 1
        // needs j>5+s of its rows; union j>s computed (lane1's extras unused).
        float gm[5][MM];
        #pragma unroll
        for (int r = 0; r < 5; ++r)
            #pragma unroll
            for (int j = 0; j < MM; ++j)
                if (j > r) gm[r][j] = 0.0f;
        #pragma unroll
        for (int ip = 0; ip < INQ; ++ip) {
            const float d = dx[ip];
            #pragma unroll
            for (int r = 0; r < 5; ++r) {
                const float4* srow = reinterpret_cast<const float4*>(
                    &skew_s[(ip * MM + r0 + r) * ROWP]);
                float4 s0 = srow[0], s1 = srow[1], s2 = srow[2];
                float row[MM] = {s0.x, s0.y, s0.z, s0.w, s1.x, s1.y, s1.z, s1.w, s2.x, s2.y};
                #pragma unroll
                for (int j = 0; j < MM; ++j)
                    if (j > r) gm[r][j] += d * row[j];
            }
        }

        // Assemble upper triangle Tri[45] of G via pair exchange.
        // Register gm[s][j]: lane0 = G[s][j], lane1 = G[5+s][j].
        // Tri[k=s][j]    (k<5):       lane0 own,  lane1 received
        // Tri[k=5+s][j]  (j>5+s):     lane0 received, lane1 own
        float Tri[45];
        #pragma unroll
        for (int sI = 0; sI < 5; ++sI) {
            #pragma unroll
            for (int j = sI + 1; j < MM; ++j) {
                const float own = gm[sI][j];
                const float rec = dpp_xor1(own);
                Tri[triIdx(sI, j)] = p ? rec : own;
                if (j > 5 + sI)
                    Tri[triIdx(5 + sI, j)] = p ? own : rec;
            }
        }

        // S-Horner: S = R; for jt=KTAY..1: S = R + S*G/jt   (row-independent)
        float S[5][MM];
        #pragma unroll
        for (int r = 0; r < 5; ++r)
            #pragma unroll
            for (int j = 0; j < MM; ++j)
                S[r][j] = R[r][j];

        #pragma unroll 1
        for (int jt = KTAY; jt >= 1; --jt) {
            const float inv = 1.0f / (float)jt;
            #pragma unroll
            for (int i = 0; i < 5; ++i) {
                float tr[MM];
                #pragma unroll
                for (int j = 0; j < MM; ++j) tr[j] = 0.0f;
                #pragma unroll
                for (int k = 0; k < MM; ++k) {
                    const float sv = S[i][k];
                    #pragma unroll
                    for (int j = 0; j < MM; ++j) {
                        if (j > k)      tr[j] += sv * Tri[triIdx(k, j)];
                        else if (j < k) tr[j] -= sv * Tri[triIdx(j, k)];
                    }
                }
                #pragma unroll
                for (int j = 0; j < MM; ++j)
                    S[i][j] = fmaf(tr[j], inv, R[i][j]);
            }
        }

        // R <- S
        #pragma unroll
        for (int r = 0; r < 5; ++r)
            #pragma unroll
            for (int j = 0; j < MM; ++j)
                R[r][j] = S[r][j];
    }

    // Store segment product to tree (padded rows, pad = 0)
    {
        float* dst = &tree_s[seg * MATP + r0 * ROWP];
        #pragma unroll
        for (int r = 0; r < 5; ++r) {
            float4* drow = reinterpret_cast<float4*>(dst + r * ROWP);
            drow[0] = make_float4(R[r][0], R[r][1], R[r][2], R[r][3]);
            drow[1] = make_float4(R[r][4], R[r][5], R[r][6], R[r][7]);
            drow[2] = make_float4(R[r][8], R[r][9], 0.0f, 0.0f);
        }
    }
    __syncthreads();

    // Dyadic tree: 7 levels; slot[q*span] <- slot[q*span] * slot[q*span+span/2]
    #pragma unroll 1
    for (int span = 2; span <= SEGS; span <<= 1) {
        const int np = SEGS / span;        // products this level
        if (tid < 2 * np) {
            const int q  = tid >> 1;
            const int pq = tid & 1;
            const int ls = q * span;
            const int rs = ls + (span >> 1);

            float lrow[5][MM];
            #pragma unroll
            for (int r = 0; r < 5; ++r) {
                const float4* lr = reinterpret_cast<const float4*>(
                    &tree_s[ls * MATP + (pq * 5 + r) * ROWP]);
                float4 a = lr[0], b = lr[1], c4 = lr[2];
                lrow[r][0] = a.x;  lrow[r][1] = a.y;  lrow[r][2] = a.z;  lrow[r][3] = a.w;
                lrow[r][4] = b.x;  lrow[r][5] = b.y;  lrow[r][6] = b.z;  lrow[r][7] = b.w;
                lrow[r][8] = c4.x; lrow[r][9] = c4.y;
            }

            float d[5][MM];
            #pragma unroll
            for (int r = 0; r < 5; ++r)
                #pragma unroll
                for (int j = 0; j < MM; ++j)
                    d[r][j] = 0.0f;

            #pragma unroll
            for (int k = 0; k < MM; ++k) {
                const float4* rr = reinterpret_cast<const float4*>(
                    &tree_s[rs * MATP + k * ROWP]);
                float4 a = rr[0], b = rr[1], c4 = rr[2];
                float rrow[MM];
                rrow[0] = a.x;  rrow[1] = a.y;  rrow[2] = a.z;  rrow[3] = a.w;
                rrow[4] = b.x;  rrow[5] = b.y;  rrow[6] = b.z;  rrow[7] = b.w;
                rrow[8] = c4.x; rrow[9] = c4.y;
                #pragma unroll
                for (int r = 0; r < 5; ++r) {
                    const float lv = lrow[r][k];
                    #pragma unroll
                    for (int j = 0; j < MM; ++j)
                        d[r][j] += lv * rrow[j];
                }
            }

            float* dst = &tree_s[ls * MATP + pq * 5 * ROWP];
            #pragma unroll
            for (int r = 0; r < 5; ++r) {
                float4* drow = reinterpret_cast<float4*>(dst + r * ROWP);
                drow[0] = make_float4(d[r][0], d[r][1], d[r][2], d[r][3]);
                drow[1] = make_float4(d[r][4], d[r][5], d[r][6], d[r][7]);
                drow[2] = make_float4(d[r][8], d[r][9], 0.0f, 0.0f);
            }
        }
        __syncthreads();
    }

    // slot 0 = chunk product -> ws (unpadded 100 floats)
    if (tid < 100) {
        const int i = tid / 10;
        const int j = tid - i * 10;
        ws[((size_t)chain * NCHUNK + chunk) * 100 + tid] = tree_s[i * ROWP + j];
    }
}

// Combine NCHUNK chunk products per chain. One thread per (chain, row).
__global__ __launch_bounds__(256) void dev_combine(const float* __restrict__ ws,
                                                   float* __restrict__ out)
{
    const int id = blockIdx.x * 256 + threadIdx.x;
    if (id >= NCHAIN * MM) return;
    const int chain = id / MM;
    const int r     = id - chain * MM;

    const float* base = ws + (size_t)chain * NCHUNK * 100;
    float R[MM];
    #pragma unroll
    for (int j = 0; j < MM; ++j) R[j] = base[r * MM + j];

    #pragma unroll
    for (int ck = 1; ck < NCHUNK; ++ck) {
        const float* Mb = base + ck * 100;
        float Rn[MM];
        #pragma unroll
        for (int j = 0; j < MM; ++j) Rn[j] = 0.0f;
        #pragma unroll
        for (int k = 0; k < MM; ++k) {
            const float rv = R[k];
            #pragma unroll
            for (int j = 0; j < MM; ++j)
                Rn[j] += rv * Mb[k * MM + j];
        }
        #pragma unroll
        for (int j = 0; j < MM; ++j) R[j] = Rn[j];
    }

    #pragma unroll
    for (int j = 0; j < MM; ++j)
        out[(size_t)chain * 100 + r * MM + j] = R[j];
}

extern "C" void kernel_launch(void* const* d_in, const int* in_sizes, int n_in,
                              void* d_out, int out_size, void* d_ws, size_t ws_size,
                              hipStream_t stream) {
    (void)in_sizes; (void)n_in; (void)out_size; (void)ws_size;
    const float* x = (const float*)d_in[0];  // (64, 2048, 8)
    const float* A = (const float*)d_in[1];  // (2, 8, 10, 10)
    float* out = (float*)d_out;              // (64, 2, 10, 10)
    float* ws  = (float*)d_ws;               // 128*4*100 floats = 204800 B

    dev_serial<<<dim3(NCHAIN * NCHUNK), dim3(256), 0, stream>>>(x, A, ws);
    dev_combine<<<dim3((NCHAIN * MM + 255) / 256), dim3(256), 0, stream>>>(ws, out);
}